// Round 7
// baseline (466.828 us; speedup 1.0000x reference)
//
#include <hip/hip_runtime.h>

#define N_NODES 50000
#define N_EDGES 1600000
#define ET (N_EDGES + N_NODES)   // edges + self-loops
#define DF 128                   // feature / hidden dim
#define SLOPE 0.2f

#define NB 196        // coarse buckets: dst >> 8 (50000/256)
#define BCAP 10240    // slots per bucket (avg 8448, sigma ~92 -> +19 sigma)
#define P1_CHUNK 4096 // edges per bin_pass block (16 per thread)

// ---------------------------------------------------------------------------
// Dual GEMM: out = X @ W.  X: [M,128] standard layout, W: [128,128].
// 128x128 block tile, 256 threads, 8x8 micro-tile, BK=32.
// OUTPUT IS HEAD-MAJOR: out[h][node][32] (h = col>>5) so the aggregation
// phase gathers 128 B rows from a 6.4 MB per-head pool (L2-resident).
// blockIdx.y: 0 -> Wl/outL, 1 -> Wr/outR.
// ---------------------------------------------------------------------------
__global__ __launch_bounds__(256) void gemm_dual(
    const float* __restrict__ X,
    const float* __restrict__ Wl, const float* __restrict__ Wr,
    float* __restrict__ outL, float* __restrict__ outR, int M)
{
    const int which = blockIdx.y;
    const float* W = which ? Wr : Wl;
    float* out = which ? outR : outL;

    __shared__ float xs[32][132];   // x tile transposed: xs[k][row]
    __shared__ float wsh[32][132];  // w tile: wsh[k][col]

    const int t  = threadIdx.x;
    const int tx = t & 15, ty = t >> 4;
    const int row0 = blockIdx.x * 128;

    float acc[8][8];
#pragma unroll
    for (int i = 0; i < 8; i++)
#pragma unroll
        for (int j = 0; j < 8; j++) acc[i][j] = 0.f;

    const int sr = t >> 1;          // 0..127 : row for X load (2 threads/row)
    const int sk = (t & 1) * 16;    // k half base for X load
    const int wk = t >> 3;          // 0..31  : k row for W load (8 threads/row)
    const int wc = (t & 7) * 16;    // col base for W load (16 cols)

    for (int kb = 0; kb < 128; kb += 32) {
        int xrw = row0 + sr; if (xrw >= M) xrw = M - 1;   // clamp; store guarded
        const float* xp = X + (size_t)xrw * DF + kb + sk;
        float4 x0 = *(const float4*)(xp + 0);
        float4 x1 = *(const float4*)(xp + 4);
        float4 x2 = *(const float4*)(xp + 8);
        float4 x3 = *(const float4*)(xp + 12);
        xs[sk + 0][sr] = x0.x;  xs[sk + 1][sr] = x0.y;
        xs[sk + 2][sr] = x0.z;  xs[sk + 3][sr] = x0.w;
        xs[sk + 4][sr] = x1.x;  xs[sk + 5][sr] = x1.y;
        xs[sk + 6][sr] = x1.z;  xs[sk + 7][sr] = x1.w;
        xs[sk + 8][sr] = x2.x;  xs[sk + 9][sr] = x2.y;
        xs[sk + 10][sr] = x2.z; xs[sk + 11][sr] = x2.w;
        xs[sk + 12][sr] = x3.x; xs[sk + 13][sr] = x3.y;
        xs[sk + 14][sr] = x3.z; xs[sk + 15][sr] = x3.w;

        const float* wp = W + (size_t)(kb + wk) * DF + wc;
        *(float4*)(&wsh[wk][wc + 0])  = *(const float4*)(wp + 0);
        *(float4*)(&wsh[wk][wc + 4])  = *(const float4*)(wp + 4);
        *(float4*)(&wsh[wk][wc + 8])  = *(const float4*)(wp + 8);
        *(float4*)(&wsh[wk][wc + 12]) = *(const float4*)(wp + 12);
        __syncthreads();
#pragma unroll
        for (int kk = 0; kk < 32; kk++) {
            float4 a0 = *(const float4*)(&xs[kk][ty * 8]);
            float4 a1 = *(const float4*)(&xs[kk][ty * 8 + 4]);
            float4 b0 = *(const float4*)(&wsh[kk][tx * 8]);
            float4 b1 = *(const float4*)(&wsh[kk][tx * 8 + 4]);
            float av[8] = {a0.x, a0.y, a0.z, a0.w, a1.x, a1.y, a1.z, a1.w};
            float bv[8] = {b0.x, b0.y, b0.z, b0.w, b1.x, b1.y, b1.z, b1.w};
#pragma unroll
            for (int i = 0; i < 8; i++)
#pragma unroll
                for (int j = 0; j < 8; j++)
                    acc[i][j] += av[i] * bv[j];
        }
        __syncthreads();
    }
    // head-major store: this thread's 8 cols (tx*8..tx*8+7) lie in head tx>>2
    const int head = tx >> 2;
    const int hc   = (tx & 3) * 8;    // channel base within head
#pragma unroll
    for (int i = 0; i < 8; i++) {
        int r = row0 + ty * 8 + i;
        if (r < M) {
            float* op = out + ((size_t)head * M + r) * 32 + hc;
            *(float4*)(op)     = make_float4(acc[i][0], acc[i][1], acc[i][2], acc[i][3]);
            *(float4*)(op + 4) = make_float4(acc[i][4], acc[i][5], acc[i][6], acc[i][7]);
        }
    }
}

// ---------------------------------------------------------------------------
// CSR build, two-level bucket sort.
// Pass 1: bin edges by coarse bucket (dst>>8). Packed 4B: src | (dst&255)<<16.
// ---------------------------------------------------------------------------
__global__ __launch_bounds__(256) void bin_pass(const int* __restrict__ ei,
                                                int* __restrict__ g_count,
                                                int* __restrict__ bucket_mem)
{
    __shared__ int cnt[NB], base[NB], cnt2[NB];
    const int tid = threadIdx.x;
    for (int i = tid; i < NB; i += 256) { cnt[i] = 0; cnt2[i] = 0; }
    __syncthreads();

    const int e0 = blockIdx.x * P1_CHUNK;
    int srcv[16], dstv[16];
#pragma unroll
    for (int i = 0; i < 16; i++) {
        int eid = e0 + i * 256 + tid;   // coalesced
        int s = 0, d = -1;
        if (eid < ET) {
            if (eid < N_EDGES) { s = ei[eid]; d = ei[N_EDGES + eid]; }
            else               { s = d = eid - N_EDGES; }
        }
        srcv[i] = s; dstv[i] = d;
        if (d >= 0) atomicAdd(&cnt[d >> 8], 1);
    }
    __syncthreads();
    for (int i = tid; i < NB; i += 256)
        base[i] = (cnt[i] > 0) ? atomicAdd(&g_count[i], cnt[i]) : 0;
    __syncthreads();
#pragma unroll
    for (int i = 0; i < 16; i++) {
        int d = dstv[i];
        if (d >= 0) {
            int b = d >> 8;
            int r = atomicAdd(&cnt2[b], 1);
            int slot = base[b] + r;
            if (slot < BCAP)
                bucket_mem[(size_t)b * BCAP + slot] =
                    (srcv[i] & 0xFFFF) | ((d & 255) << 16);
        }
    }
}

// Pass 2: one block per bucket. Inline scan of bucket counts, LDS-stage edges,
// local 256-node hist + scan (row_ptr direct), scatter csr_src (ushort).
__global__ __launch_bounds__(256) void csr_pass(const int* __restrict__ g_count,
                                                const int* __restrict__ bucket_mem,
                                                int* __restrict__ row_ptr,
                                                unsigned short* __restrict__ csr_src)
{
    __shared__ int sh_edges[BCAP];
    __shared__ int hist[256], offs[256], excl[256], cnt2[256];
    __shared__ int gsc[256];
    const int b = blockIdx.x, tid = threadIdx.x;

    gsc[tid] = (tid < NB) ? g_count[tid] : 0;
    __syncthreads();
    for (int d = 1; d < 256; d <<= 1) {
        int x = (tid >= d) ? gsc[tid - d] : 0;
        __syncthreads();
        gsc[tid] += x;
        __syncthreads();
    }
    const int base_csr = (b > 0) ? gsc[b - 1] : 0;

    int m = g_count[b]; if (m > BCAP) m = BCAP;
    hist[tid] = 0; cnt2[tid] = 0;
    __syncthreads();
    const int* bm = bucket_mem + (size_t)b * BCAP;
    for (int i = tid; i < m; i += 256) {
        int p = bm[i];
        sh_edges[i] = p;
        atomicAdd(&hist[(p >> 16) & 255], 1);
    }
    __syncthreads();
    offs[tid] = hist[tid]; __syncthreads();
    for (int d = 1; d < 256; d <<= 1) {
        int x = (tid >= d) ? offs[tid - d] : 0;
        __syncthreads();
        offs[tid] += x;
        __syncthreads();
    }
    excl[tid] = offs[tid] - hist[tid];
    const int node0 = b << 8;
    if (node0 + tid < N_NODES) row_ptr[node0 + tid] = base_csr + excl[tid];
    if (b == 0 && tid == 0) row_ptr[N_NODES] = ET;
    __syncthreads();
    for (int i = tid; i < m; i += 256) {
        int p = sh_edges[i];
        int dl = (p >> 16) & 255;
        int r = atomicAdd(&cnt2[dl], 1);
        csr_src[base_csr + excl[dl] + r] = (unsigned short)(p & 0xFFFF);
    }
}

// ---------------------------------------------------------------------------
// Head-split fused scores + softmax + aggregate.
// grid = (ceil(N/4), 4): blockIdx.y = head (x-major dispatch keeps one head's
// 6.4 MB pool L2-resident per phase). One wave per (node, head).
// 8 lanes per edge (float4 = 4 ch/lane over the head's 32 ch); 8 edges in
// flight per wave iteration. xl/xr are head-major [h][n][32]; out standard.
// ---------------------------------------------------------------------------
__global__ __launch_bounds__(256) void fused_agg(
    const float* __restrict__ XL, const float* __restrict__ XR,
    const int* __restrict__ row_ptr, const unsigned short* __restrict__ csr_src,
    const float* __restrict__ att, const float* __restrict__ bias,
    float* __restrict__ out)
{
    const int t = threadIdx.x;
    const int wave = t >> 6, l = t & 63;
    const int g = l >> 3, gl = l & 7;        // edge group 0..7, lane in group
    const int h = blockIdx.y;
    const int n = blockIdx.x * 4 + wave;
    if (n >= N_NODES) return;
    const int beg = row_ptr[n], end = row_ptr[n + 1];

    const float* xlh = XL + (size_t)h * N_NODES * 32;
    const int c0 = gl * 4;                   // channel within head
    float4 xrv = *(const float4*)(XR + ((size_t)h * N_NODES + n) * 32 + c0);
    float4 atv = *(const float4*)(att + h * 32 + c0);

    float a0 = 0.f, a1 = 0.f, a2 = 0.f, a3 = 0.f, den = 0.f;

    for (int base = beg; base < end; base += 64) {
        int cnt = end - base; if (cnt > 64) cnt = 64;
        int my_src = 0;
        if (base + l < end) my_src = csr_src[base + l];   // coalesced batch load
        int jmax = (cnt + 7) >> 3;
        for (int j = 0; j < jmax; j++) {
            int eidx = j * 8 + g;
            int s = __shfl(my_src, eidx);                 // garbage->row0 if OOB
            float4 v = *(const float4*)(xlh + (size_t)s * 32 + c0);
            float m0 = v.x + xrv.x, m1 = v.y + xrv.y;
            float m2 = v.z + xrv.z, m3 = v.w + xrv.w;
            m0 = m0 > 0.f ? m0 : SLOPE * m0;
            m1 = m1 > 0.f ? m1 : SLOPE * m1;
            m2 = m2 > 0.f ? m2 : SLOPE * m2;
            m3 = m3 > 0.f ? m3 : SLOPE * m3;
            float p = m0 * atv.x + m1 * atv.y + m2 * atv.z + m3 * atv.w;
            // reduce over the 8 lanes of this edge group
            p += __shfl_xor(p, 1);
            p += __shfl_xor(p, 2);
            p += __shfl_xor(p, 4);
            float e = (eidx < cnt) ? __expf(p) : 0.f;
            a0 += e * v.x; a1 += e * v.y; a2 += e * v.z; a3 += e * v.w;
            den += e;
        }
    }

    // combine the 8 edge-group accumulators (same channels, different edges)
#define CMB(x) x += __shfl_xor(x, 8); x += __shfl_xor(x, 16); x += __shfl_xor(x, 32);
    CMB(a0) CMB(a1) CMB(a2) CMB(a3) CMB(den)
#undef CMB

    if (g == 0) {
        float inv = 1.f / (den + 1e-16f);
        float4 bv = *(const float4*)(bias + h * 32 + c0);
        float4 o;
        o.x = fmaxf(a0 * inv + bv.x, 0.f);
        o.y = fmaxf(a1 * inv + bv.y, 0.f);
        o.z = fmaxf(a2 * inv + bv.z, 0.f);
        o.w = fmaxf(a3 * inv + bv.w, 0.f);
        *(float4*)(out + (size_t)n * DF + h * 32 + c0) = o;
    }
}

// ---------------------------------------------------------------------------
extern "C" void kernel_launch(void* const* d_in, const int* in_sizes, int n_in,
                              void* d_out, int out_size, void* d_ws, size_t ws_size,
                              hipStream_t stream)
{
    (void)in_sizes; (void)n_in; (void)out_size; (void)ws_size;

    const float* x    = (const float*)d_in[0];
    const int*   ei   = (const int*)d_in[1];
    const float* W1l  = (const float*)d_in[2];
    const float* W1r  = (const float*)d_in[3];
    const float* att1 = (const float*)d_in[4];
    const float* b1   = (const float*)d_in[5];
    const float* W2l  = (const float*)d_in[6];
    const float* W2r  = (const float*)d_in[7];
    const float* att2 = (const float*)d_in[8];
    const float* b2   = (const float*)d_in[9];
    float* out = (float*)d_out;

    char* ws = (char*)d_ws;
    size_t off = 0;
    const size_t NF = (size_t)N_NODES * DF * sizeof(float);   // 25.6 MB
    float* A  = (float*)(ws + off); off += NF;                // xl (head-major)
    float* B  = (float*)(ws + off); off += NF;                // xr (head-major)
    float* C  = (float*)(ws + off); off += NF;                // layer-1 output h (standard)
    int* bucket_mem  = (int*)(ws + off); off += (size_t)NB * BCAP * sizeof(int);
    int* g_count     = (int*)(ws + off); off += 256 * sizeof(int);
    int* row_ptr     = (int*)(ws + off); off += (size_t)(N_NODES + 1) * sizeof(int);
    unsigned short* csr_src = (unsigned short*)(ws + off);
    off += ((size_t)ET * sizeof(unsigned short) + 3) & ~(size_t)3;

    // ---- CSR over dst (shared by both layers) ----
    hipMemsetAsync(g_count, 0, NB * sizeof(int), stream);
    bin_pass<<<(ET + P1_CHUNK - 1) / P1_CHUNK, 256, 0, stream>>>(ei, g_count, bucket_mem);
    csr_pass<<<NB, 256, 0, stream>>>(g_count, bucket_mem, row_ptr, csr_src);

    dim3 gg((N_NODES + 127) / 128, 2);
    dim3 ga((N_NODES + 3) / 4, 4);

    // ---- layer 1 ----
    gemm_dual<<<gg, 256, 0, stream>>>(x, W1l, W1r, A, B, N_NODES);
    fused_agg<<<ga, 256, 0, stream>>>(A, B, row_ptr, csr_src, att1, b1, C);

    // ---- layer 2 ----
    gemm_dual<<<gg, 256, 0, stream>>>(C, W2l, W2r, A, B, N_NODES);
    fused_agg<<<ga, 256, 0, stream>>>(A, B, row_ptr, csr_src, att2, b2, out);
}

// Round 8
// 369.782 us; speedup vs baseline: 1.2624x; 1.2624x over previous
//
#include <hip/hip_runtime.h>

#define N_NODES 50000
#define N_EDGES 1600000
#define ET (N_EDGES + N_NODES)   // edges + self-loops
#define DF 128                   // feature / hidden dim
#define SLOPE 0.2f

#define NB 196        // coarse buckets: dst >> 8 (50000/256)
#define BCAP 10240    // slots per bucket (avg 8448, sigma ~92 -> +19 sigma)
#define P1_CHUNK 4096 // edges per bin_pass block (16 per thread)

typedef __attribute__((ext_vector_type(8))) short bf16x8;   // 8 bf16 (4 VGPRs)
typedef __attribute__((ext_vector_type(4))) float floatx4;  // MFMA C/D

__device__ inline unsigned short f2bf(float v) {            // RNE fp32->bf16
    unsigned int u = __float_as_uint(v);
    u += 0x7FFF + ((u >> 16) & 1);
    return (unsigned short)(u >> 16);
}
__device__ inline void splitbf(float v, unsigned short& h, unsigned short& l) {
    h = f2bf(v);
    float hf = __uint_as_float((unsigned int)h << 16);
    l = f2bf(v - hf);   // residual; hi+lo carries ~16-17 mantissa bits
}

// ---------------------------------------------------------------------------
// One-time W prep: split each 128x128 W (layout [k][c]) into hi/lo bf16,
// stored TRANSPOSED as [c][k] so gemm_mfma B-fragments are contiguous b128.
// blockIdx.y = matrix index {W1l, W1r, W2l, W2r}.
// ---------------------------------------------------------------------------
__global__ __launch_bounds__(256) void wconv4(
    const float* __restrict__ W0, const float* __restrict__ W1,
    const float* __restrict__ W2, const float* __restrict__ W3,
    unsigned short* __restrict__ Wh, unsigned short* __restrict__ Wl)
{
    const int m = blockIdx.y;
    const float* W = (m == 0) ? W0 : (m == 1) ? W1 : (m == 2) ? W2 : W3;
    int idx = blockIdx.x * 256 + threadIdx.x;   // 0..16383
    int c = idx >> 7, k = idx & 127;
    float v = W[k * 128 + c];
    unsigned short h, l;
    splitbf(v, h, l);
    Wh[(size_t)m * 16384 + c * 128 + k] = h;
    Wl[(size_t)m * 16384 + c * 128 + k] = l;
}

// ---------------------------------------------------------------------------
// Split-bf16 MFMA GEMM: out = X @ W, X [M][128] fp32, W via hi/lo bf16.
// acc += Ah*Bh + Ah*Bl + Al*Bh  (Al*Bl term ~2^-18, dropped).
// Block: 64 rows x 128 cols, 4 waves; wave = 16 rows x 8 col-tiles of 16.
// mfma_f32_16x16x32_bf16: A[m=lane&15][k=quad*8+j], B[k=quad*8+j][n=lane&15],
// D row=quad*4+reg, col=lane&15  (m89/m91-verified layouts).
// OUTPUT IS HEAD-PAIR-MAJOR: out[pair][row][64], pair = col>>6.
// blockIdx.y: 0 -> L, 1 -> R.
// ---------------------------------------------------------------------------
__global__ __launch_bounds__(256) void gemm_mfma(
    const float* __restrict__ X,
    const unsigned short* __restrict__ WhL, const unsigned short* __restrict__ WlL,
    const unsigned short* __restrict__ WhR, const unsigned short* __restrict__ WlR,
    float* __restrict__ outL, float* __restrict__ outR, int M)
{
    const int which = blockIdx.y;
    const unsigned short* Wh = which ? WhR : WhL;
    const unsigned short* Wl = which ? WlR : WlL;
    float* out = which ? outR : outL;

    // stride 40 bf16 (80 B) rows: lanes hit banks r*20%32 -> worst 2-way (free)
    __shared__ unsigned short xh[64 * 40], xl[64 * 40];
    __shared__ unsigned short wh[128 * 40], wl[128 * 40];

    const int t = threadIdx.x;
    const int row0 = blockIdx.x * 64;
    const int lane = t & 63, wv = t >> 6;
    const int lm = lane & 15, quad = lane >> 4;
    const int m0 = wv * 16;

    floatx4 acc[8];
#pragma unroll
    for (int i = 0; i < 8; i++) acc[i] = (floatx4)0.f;

    const int sr = t >> 2;          // X stage: row 0..63 (4 thr/row)
    const int sc = (t & 3) * 8;     // X stage: k offset
    const int wn = t >> 1;          // W stage: col 0..127 (2 thr/col)
    const int wkh = (t & 1) * 16;   // W stage: k half

    for (int kb = 0; kb < 128; kb += 32) {
        int xrow = row0 + sr; if (xrow >= M) xrow = M - 1;  // clamp; store guarded
        const float* xp = X + (size_t)xrow * DF + kb + sc;
        float4 v0 = *(const float4*)(xp);
        float4 v1 = *(const float4*)(xp + 4);
        ushort4 h0, h1, l0, l1;
        splitbf(v0.x, h0.x, l0.x); splitbf(v0.y, h0.y, l0.y);
        splitbf(v0.z, h0.z, l0.z); splitbf(v0.w, h0.w, l0.w);
        splitbf(v1.x, h1.x, l1.x); splitbf(v1.y, h1.y, l1.y);
        splitbf(v1.z, h1.z, l1.z); splitbf(v1.w, h1.w, l1.w);
        *(ushort4*)&xh[sr * 40 + sc]     = h0;
        *(ushort4*)&xh[sr * 40 + sc + 4] = h1;
        *(ushort4*)&xl[sr * 40 + sc]     = l0;
        *(ushort4*)&xl[sr * 40 + sc + 4] = l1;

        const uint4* whp = (const uint4*)(Wh + (size_t)wn * 128 + kb + wkh);
        const uint4* wlp = (const uint4*)(Wl + (size_t)wn * 128 + kb + wkh);
        uint4 wa0 = whp[0], wa1 = whp[1];
        uint4 wb0 = wlp[0], wb1 = wlp[1];
        *(uint4*)&wh[wn * 40 + wkh]     = wa0;
        *(uint4*)&wh[wn * 40 + wkh + 8] = wa1;
        *(uint4*)&wl[wn * 40 + wkh]     = wb0;
        *(uint4*)&wl[wn * 40 + wkh + 8] = wb1;
        __syncthreads();

        bf16x8 ahf = *(const bf16x8*)&xh[(m0 + lm) * 40 + quad * 8];
        bf16x8 alf = *(const bf16x8*)&xl[(m0 + lm) * 40 + quad * 8];
#pragma unroll
        for (int nt = 0; nt < 8; nt++) {
            bf16x8 bhf = *(const bf16x8*)&wh[(nt * 16 + lm) * 40 + quad * 8];
            bf16x8 blf = *(const bf16x8*)&wl[(nt * 16 + lm) * 40 + quad * 8];
            acc[nt] = __builtin_amdgcn_mfma_f32_16x16x32_bf16(ahf, bhf, acc[nt], 0, 0, 0);
            acc[nt] = __builtin_amdgcn_mfma_f32_16x16x32_bf16(ahf, blf, acc[nt], 0, 0, 0);
            acc[nt] = __builtin_amdgcn_mfma_f32_16x16x32_bf16(alf, bhf, acc[nt], 0, 0, 0);
        }
        __syncthreads();
    }

#pragma unroll
    for (int nt = 0; nt < 8; nt++) {
        int colpair = nt >> 2;
        int coloff  = (nt & 3) * 16 + lm;
#pragma unroll
        for (int r = 0; r < 4; r++) {
            int gr = row0 + m0 + quad * 4 + r;
            if (gr < M)
                out[((size_t)colpair * M + gr) * 64 + coloff] = acc[nt][r];
        }
    }
}

// ---------------------------------------------------------------------------
// CSR build, two-level bucket sort (unchanged from R6).
// ---------------------------------------------------------------------------
__global__ __launch_bounds__(256) void bin_pass(const int* __restrict__ ei,
                                                int* __restrict__ g_count,
                                                int* __restrict__ bucket_mem)
{
    __shared__ int cnt[NB], base[NB], cnt2[NB];
    const int tid = threadIdx.x;
    for (int i = tid; i < NB; i += 256) { cnt[i] = 0; cnt2[i] = 0; }
    __syncthreads();

    const int e0 = blockIdx.x * P1_CHUNK;
    int srcv[16], dstv[16];
#pragma unroll
    for (int i = 0; i < 16; i++) {
        int eid = e0 + i * 256 + tid;   // coalesced
        int s = 0, d = -1;
        if (eid < ET) {
            if (eid < N_EDGES) { s = ei[eid]; d = ei[N_EDGES + eid]; }
            else               { s = d = eid - N_EDGES; }
        }
        srcv[i] = s; dstv[i] = d;
        if (d >= 0) atomicAdd(&cnt[d >> 8], 1);
    }
    __syncthreads();
    for (int i = tid; i < NB; i += 256)
        base[i] = (cnt[i] > 0) ? atomicAdd(&g_count[i], cnt[i]) : 0;
    __syncthreads();
#pragma unroll
    for (int i = 0; i < 16; i++) {
        int d = dstv[i];
        if (d >= 0) {
            int b = d >> 8;
            int r = atomicAdd(&cnt2[b], 1);
            int slot = base[b] + r;
            if (slot < BCAP)
                bucket_mem[(size_t)b * BCAP + slot] =
                    (srcv[i] & 0xFFFF) | ((d & 255) << 16);
        }
    }
}

__global__ __launch_bounds__(256) void csr_pass(const int* __restrict__ g_count,
                                                const int* __restrict__ bucket_mem,
                                                int* __restrict__ row_ptr,
                                                unsigned short* __restrict__ csr_src)
{
    __shared__ int sh_edges[BCAP];
    __shared__ int hist[256], offs[256], excl[256], cnt2[256];
    __shared__ int gsc[256];
    const int b = blockIdx.x, tid = threadIdx.x;

    gsc[tid] = (tid < NB) ? g_count[tid] : 0;
    __syncthreads();
    for (int d = 1; d < 256; d <<= 1) {
        int x = (tid >= d) ? gsc[tid - d] : 0;
        __syncthreads();
        gsc[tid] += x;
        __syncthreads();
    }
    const int base_csr = (b > 0) ? gsc[b - 1] : 0;

    int m = g_count[b]; if (m > BCAP) m = BCAP;
    hist[tid] = 0; cnt2[tid] = 0;
    __syncthreads();
    const int* bm = bucket_mem + (size_t)b * BCAP;
    for (int i = tid; i < m; i += 256) {
        int p = bm[i];
        sh_edges[i] = p;
        atomicAdd(&hist[(p >> 16) & 255], 1);
    }
    __syncthreads();
    offs[tid] = hist[tid]; __syncthreads();
    for (int d = 1; d < 256; d <<= 1) {
        int x = (tid >= d) ? offs[tid - d] : 0;
        __syncthreads();
        offs[tid] += x;
        __syncthreads();
    }
    excl[tid] = offs[tid] - hist[tid];
    const int node0 = b << 8;
    if (node0 + tid < N_NODES) row_ptr[node0 + tid] = base_csr + excl[tid];
    if (b == 0 && tid == 0) row_ptr[N_NODES] = ET;
    __syncthreads();
    for (int i = tid; i < m; i += 256) {
        int p = sh_edges[i];
        int dl = (p >> 16) & 255;
        int r = atomicAdd(&cnt2[dl], 1);
        csr_src[base_csr + excl[dl] + r] = (unsigned short)(p & 0xFFFF);
    }
}

// ---------------------------------------------------------------------------
// Head-PAIR fused scores + softmax + aggregate.
// grid = (ceil(N/4), 2): blockIdx.y = head pair (12.8 MB pool per phase).
// One wave per (node, pair). 8 lanes/edge, lane covers 8 ch of the pair's 64
// (lanes 0-3 -> head 2p, 4-7 -> head 2p+1). 8 edges in flight per iteration.
// XL/XR pair-major [2][N][64]; out standard [N][128].
// ---------------------------------------------------------------------------
__global__ __launch_bounds__(256) void fused_agg(
    const float* __restrict__ XL, const float* __restrict__ XR,
    const int* __restrict__ row_ptr, const unsigned short* __restrict__ csr_src,
    const float* __restrict__ att, const float* __restrict__ bias,
    float* __restrict__ out)
{
    const int t = threadIdx.x;
    const int wave = t >> 6, l = t & 63;
    const int g = l >> 3, gl = l & 7;        // edge group 0..7, lane in group
    const int hp = blockIdx.y;               // head pair
    const int n = blockIdx.x * 4 + wave;
    if (n >= N_NODES) return;
    const int beg = row_ptr[n], end = row_ptr[n + 1];

    const float* xlp = XL + (size_t)hp * N_NODES * 64;
    const int c0 = gl * 8;                   // channel within pair (0..56)
    const float* xrp = XR + ((size_t)hp * N_NODES + n) * 64 + c0;
    float4 xr0 = *(const float4*)(xrp);
    float4 xr1 = *(const float4*)(xrp + 4);
    float4 at0 = *(const float4*)(att + hp * 64 + c0);
    float4 at1 = *(const float4*)(att + hp * 64 + c0 + 4);

    float a0 = 0.f, a1 = 0.f, a2 = 0.f, a3 = 0.f;
    float a4 = 0.f, a5 = 0.f, a6 = 0.f, a7 = 0.f, den = 0.f;

    for (int base = beg; base < end; base += 64) {
        int cnt = end - base; if (cnt > 64) cnt = 64;
        int my_src = 0;
        if (base + l < end) my_src = csr_src[base + l];   // coalesced batch load
        int jmax = (cnt + 7) >> 3;
        for (int j = 0; j < jmax; j++) {
            int eidx = j * 8 + g;
            int s = __shfl(my_src, eidx);                 // row 0 if OOB (masked)
            const float* row = xlp + (size_t)s * 64 + c0;
            float4 v0 = *(const float4*)(row);
            float4 v1 = *(const float4*)(row + 4);
            float m0 = v0.x + xr0.x, m1 = v0.y + xr0.y;
            float m2 = v0.z + xr0.z, m3 = v0.w + xr0.w;
            float m4 = v1.x + xr1.x, m5 = v1.y + xr1.y;
            float m6 = v1.z + xr1.z, m7 = v1.w + xr1.w;
            m0 = m0 > 0.f ? m0 : SLOPE * m0;  m1 = m1 > 0.f ? m1 : SLOPE * m1;
            m2 = m2 > 0.f ? m2 : SLOPE * m2;  m3 = m3 > 0.f ? m3 : SLOPE * m3;
            m4 = m4 > 0.f ? m4 : SLOPE * m4;  m5 = m5 > 0.f ? m5 : SLOPE * m5;
            m6 = m6 > 0.f ? m6 : SLOPE * m6;  m7 = m7 > 0.f ? m7 : SLOPE * m7;
            float p = m0 * at0.x + m1 * at0.y + m2 * at0.z + m3 * at0.w
                    + m4 * at1.x + m5 * at1.y + m6 * at1.z + m7 * at1.w;
            // per-head reduce: lanes {0-3} = head 2hp, {4-7} = head 2hp+1
            p += __shfl_xor(p, 1);
            p += __shfl_xor(p, 2);
            float e = (eidx < cnt) ? __expf(p) : 0.f;
            a0 += e * v0.x; a1 += e * v0.y; a2 += e * v0.z; a3 += e * v0.w;
            a4 += e * v1.x; a5 += e * v1.y; a6 += e * v1.z; a7 += e * v1.w;
            den += e;
        }
    }

    // combine the 8 edge-group accumulators (same channels, different edges)
#define CMB(x) x += __shfl_xor(x, 8); x += __shfl_xor(x, 16); x += __shfl_xor(x, 32);
    CMB(a0) CMB(a1) CMB(a2) CMB(a3) CMB(a4) CMB(a5) CMB(a6) CMB(a7) CMB(den)
#undef CMB

    if (g == 0) {
        float inv = 1.f / (den + 1e-16f);
        const float* bp = bias + hp * 64 + c0;
        float4 b0 = *(const float4*)(bp);
        float4 b1 = *(const float4*)(bp + 4);
        float4 o0, o1;
        o0.x = fmaxf(a0 * inv + b0.x, 0.f);
        o0.y = fmaxf(a1 * inv + b0.y, 0.f);
        o0.z = fmaxf(a2 * inv + b0.z, 0.f);
        o0.w = fmaxf(a3 * inv + b0.w, 0.f);
        o1.x = fmaxf(a4 * inv + b1.x, 0.f);
        o1.y = fmaxf(a5 * inv + b1.y, 0.f);
        o1.z = fmaxf(a6 * inv + b1.z, 0.f);
        o1.w = fmaxf(a7 * inv + b1.w, 0.f);
        float* op = out + (size_t)n * DF + hp * 64 + c0;
        *(float4*)(op)     = o0;
        *(float4*)(op + 4) = o1;
    }
}

// ---------------------------------------------------------------------------
extern "C" void kernel_launch(void* const* d_in, const int* in_sizes, int n_in,
                              void* d_out, int out_size, void* d_ws, size_t ws_size,
                              hipStream_t stream)
{
    (void)in_sizes; (void)n_in; (void)out_size; (void)ws_size;

    const float* x    = (const float*)d_in[0];
    const int*   ei   = (const int*)d_in[1];
    const float* W1l  = (const float*)d_in[2];
    const float* W1r  = (const float*)d_in[3];
    const float* att1 = (const float*)d_in[4];
    const float* b1   = (const float*)d_in[5];
    const float* W2l  = (const float*)d_in[6];
    const float* W2r  = (const float*)d_in[7];
    const float* att2 = (const float*)d_in[8];
    const float* b2   = (const float*)d_in[9];
    float* out = (float*)d_out;

    char* ws = (char*)d_ws;
    size_t off = 0;
    const size_t NF = (size_t)N_NODES * DF * sizeof(float);   // 25.6 MB
    float* A  = (float*)(ws + off); off += NF;                // xl, pair-major
    float* B  = (float*)(ws + off); off += NF;                // xr, pair-major
    float* C  = (float*)(ws + off); off += NF;                // layer-1 out (std)
    int* bucket_mem  = (int*)(ws + off); off += (size_t)NB * BCAP * sizeof(int);
    int* g_count     = (int*)(ws + off); off += 256 * sizeof(int);
    int* row_ptr     = (int*)(ws + off); off += (size_t)(N_NODES + 1) * sizeof(int);
    unsigned short* csr_src = (unsigned short*)(ws + off);
    off += ((size_t)ET * sizeof(unsigned short) + 255) & ~(size_t)255;
    unsigned short* Wh = (unsigned short*)(ws + off); off += 4 * 16384 * sizeof(unsigned short);
    unsigned short* Wl = (unsigned short*)(ws + off); off += 4 * 16384 * sizeof(unsigned short);

    // ---- one-time prep ----
    hipMemsetAsync(g_count, 0, NB * sizeof(int), stream);
    wconv4<<<dim3(64, 4), 256, 0, stream>>>(W1l, W1r, W2l, W2r, Wh, Wl);
    bin_pass<<<(ET + P1_CHUNK - 1) / P1_CHUNK, 256, 0, stream>>>(ei, g_count, bucket_mem);
    csr_pass<<<NB, 256, 0, stream>>>(g_count, bucket_mem, row_ptr, csr_src);

    dim3 gg((N_NODES + 63) / 64, 2);
    dim3 ga((N_NODES + 3) / 4, 2);

    // ---- layer 1 ----
    gemm_mfma<<<gg, 256, 0, stream>>>(x, Wh, Wl, Wh + 16384, Wl + 16384, A, B, N_NODES);
    fused_agg<<<ga, 256, 0, stream>>>(A, B, row_ptr, csr_src, att1, b1, C);

    // ---- layer 2 ----
    gemm_mfma<<<gg, 256, 0, stream>>>(C, Wh + 2 * 16384, Wl + 2 * 16384,
                                      Wh + 3 * 16384, Wl + 3 * 16384, A, B, N_NODES);
    fused_agg<<<ga, 256, 0, stream>>>(A, B, row_ptr, csr_src, att2, b2, out);
}

// Round 9
// 351.022 us; speedup vs baseline: 1.3299x; 1.0534x over previous
//
#include <hip/hip_runtime.h>

#define N_NODES 50000
#define N_EDGES 1600000
#define ET (N_EDGES + N_NODES)   // edges + self-loops
#define DF 128                   // feature / hidden dim
#define SLOPE 0.2f

#define NB 196        // coarse buckets: dst >> 8 (50000/256)
#define BCAP 10240    // slots per bucket (avg 8448, sigma ~92 -> +19 sigma)
#define P1_CHUNK 4096 // edges per bin_pass block (16 per thread)

typedef __attribute__((ext_vector_type(8))) short bf16x8;      // 8 bf16 (4 VGPRs)
typedef __attribute__((ext_vector_type(4))) float floatx4;     // MFMA C/D
typedef __attribute__((ext_vector_type(8))) _Float16 half8;    // 8 fp16 (16 B)

__device__ inline unsigned short f2bf(float v) {               // RNE fp32->bf16
    unsigned int u = __float_as_uint(v);
    u += 0x7FFF + ((u >> 16) & 1);
    return (unsigned short)(u >> 16);
}
__device__ inline void splitbf(float v, unsigned short& h, unsigned short& l) {
    h = f2bf(v);
    float hf = __uint_as_float((unsigned int)h << 16);
    l = f2bf(v - hf);   // residual; hi+lo carries ~16-17 mantissa bits
}

// ---------------------------------------------------------------------------
// One-time W prep: split each 128x128 W (layout [k][c]) into hi/lo bf16,
// stored TRANSPOSED as [c][k]. blockIdx.y = matrix {W1l, W1r, W2l, W2r}.
// Block (0,0) also zeroes g_count (folds the old memset dispatch).
// ---------------------------------------------------------------------------
__global__ __launch_bounds__(256) void wconv4(
    const float* __restrict__ W0, const float* __restrict__ W1,
    const float* __restrict__ W2, const float* __restrict__ W3,
    unsigned short* __restrict__ Wh, unsigned short* __restrict__ Wl,
    int* __restrict__ g_count)
{
    if (blockIdx.x == 0 && blockIdx.y == 0) g_count[threadIdx.x] = 0;
    const int m = blockIdx.y;
    const float* W = (m == 0) ? W0 : (m == 1) ? W1 : (m == 2) ? W2 : W3;
    int idx = blockIdx.x * 256 + threadIdx.x;   // 0..16383
    int c = idx >> 7, k = idx & 127;
    float v = W[k * 128 + c];
    unsigned short h, l;
    splitbf(v, h, l);
    Wh[(size_t)m * 16384 + c * 128 + k] = h;
    Wl[(size_t)m * 16384 + c * 128 + k] = l;
}

// ---------------------------------------------------------------------------
// Split-bf16 MFMA GEMM, L+R merged: stage/split X ONCE, run both weight sets.
// acc += Ah*Bh + Ah*Bl + Al*Bh  (Al*Bl ~2^-18, dropped).
// Block: 64 rows x (128 L-cols + 128 R-cols), 4 waves, 48 MFMA / K-iter.
// outL is fp16 pair-major [2][M][64] (the gather operand: 6.4 MB/pair pool);
// outR is fp32 pair-major [2][M][64].
// ---------------------------------------------------------------------------
__global__ __launch_bounds__(256) void gemm_mfma(
    const float* __restrict__ X,
    const unsigned short* __restrict__ WhL, const unsigned short* __restrict__ WlL,
    const unsigned short* __restrict__ WhR, const unsigned short* __restrict__ WlR,
    _Float16* __restrict__ outL, float* __restrict__ outR, int M)
{
    // stride 40 bf16 (80 B) rows: worst 2-way bank alias (free)
    __shared__ unsigned short xh[64 * 40], xl[64 * 40];          // 10 KB
    __shared__ unsigned short whL[128 * 40], wlL[128 * 40];      // 20 KB
    __shared__ unsigned short whR[128 * 40], wlR[128 * 40];      // 20 KB

    const int t = threadIdx.x;
    const int row0 = blockIdx.x * 64;
    const int lane = t & 63, wv = t >> 6;
    const int lm = lane & 15, quad = lane >> 4;
    const int m0 = wv * 16;

    floatx4 accL[8], accR[8];
#pragma unroll
    for (int i = 0; i < 8; i++) { accL[i] = (floatx4)0.f; accR[i] = (floatx4)0.f; }

    const int sr = t >> 2;          // X stage: row 0..63 (4 thr/row)
    const int sc = (t & 3) * 8;     // X stage: k offset
    const int wn = t >> 1;          // W stage: col 0..127 (2 thr/col)
    const int wkh = (t & 1) * 16;   // W stage: k half

    for (int kb = 0; kb < 128; kb += 32) {
        int xrow = row0 + sr; if (xrow >= M) xrow = M - 1;  // clamp; store guarded
        const float* xp = X + (size_t)xrow * DF + kb + sc;
        float4 v0 = *(const float4*)(xp);
        float4 v1 = *(const float4*)(xp + 4);
        ushort4 h0, h1, l0, l1;
        splitbf(v0.x, h0.x, l0.x); splitbf(v0.y, h0.y, l0.y);
        splitbf(v0.z, h0.z, l0.z); splitbf(v0.w, h0.w, l0.w);
        splitbf(v1.x, h1.x, l1.x); splitbf(v1.y, h1.y, l1.y);
        splitbf(v1.z, h1.z, l1.z); splitbf(v1.w, h1.w, l1.w);
        *(ushort4*)&xh[sr * 40 + sc]     = h0;
        *(ushort4*)&xh[sr * 40 + sc + 4] = h1;
        *(ushort4*)&xl[sr * 40 + sc]     = l0;
        *(ushort4*)&xl[sr * 40 + sc + 4] = l1;

        const size_t wofs = (size_t)wn * 128 + kb + wkh;
        {
            const uint4* p = (const uint4*)(WhL + wofs);
            uint4 a = p[0], b = p[1];
            *(uint4*)&whL[wn * 40 + wkh] = a; *(uint4*)&whL[wn * 40 + wkh + 8] = b;
        }
        {
            const uint4* p = (const uint4*)(WlL + wofs);
            uint4 a = p[0], b = p[1];
            *(uint4*)&wlL[wn * 40 + wkh] = a; *(uint4*)&wlL[wn * 40 + wkh + 8] = b;
        }
        {
            const uint4* p = (const uint4*)(WhR + wofs);
            uint4 a = p[0], b = p[1];
            *(uint4*)&whR[wn * 40 + wkh] = a; *(uint4*)&whR[wn * 40 + wkh + 8] = b;
        }
        {
            const uint4* p = (const uint4*)(WlR + wofs);
            uint4 a = p[0], b = p[1];
            *(uint4*)&wlR[wn * 40 + wkh] = a; *(uint4*)&wlR[wn * 40 + wkh + 8] = b;
        }
        __syncthreads();

        bf16x8 ahf = *(const bf16x8*)&xh[(m0 + lm) * 40 + quad * 8];
        bf16x8 alf = *(const bf16x8*)&xl[(m0 + lm) * 40 + quad * 8];
#pragma unroll
        for (int nt = 0; nt < 8; nt++) {
            const int bofs = (nt * 16 + lm) * 40 + quad * 8;
            bf16x8 bh = *(const bf16x8*)&whL[bofs];
            bf16x8 bl = *(const bf16x8*)&wlL[bofs];
            accL[nt] = __builtin_amdgcn_mfma_f32_16x16x32_bf16(ahf, bh, accL[nt], 0, 0, 0);
            accL[nt] = __builtin_amdgcn_mfma_f32_16x16x32_bf16(ahf, bl, accL[nt], 0, 0, 0);
            accL[nt] = __builtin_amdgcn_mfma_f32_16x16x32_bf16(alf, bh, accL[nt], 0, 0, 0);
            bf16x8 ch = *(const bf16x8*)&whR[bofs];
            bf16x8 cl = *(const bf16x8*)&wlR[bofs];
            accR[nt] = __builtin_amdgcn_mfma_f32_16x16x32_bf16(ahf, ch, accR[nt], 0, 0, 0);
            accR[nt] = __builtin_amdgcn_mfma_f32_16x16x32_bf16(ahf, cl, accR[nt], 0, 0, 0);
            accR[nt] = __builtin_amdgcn_mfma_f32_16x16x32_bf16(alf, ch, accR[nt], 0, 0, 0);
        }
        __syncthreads();
    }

#pragma unroll
    for (int nt = 0; nt < 8; nt++) {
        int colpair = nt >> 2;
        int coloff  = (nt & 3) * 16 + lm;
#pragma unroll
        for (int r = 0; r < 4; r++) {
            int gr = row0 + m0 + quad * 4 + r;
            if (gr < M) {
                size_t o = ((size_t)colpair * M + gr) * 64 + coloff;
                outL[o] = (_Float16)accL[nt][r];
                outR[o] = accR[nt][r];
            }
        }
    }
}

// ---------------------------------------------------------------------------
// CSR build, two-level bucket sort (unchanged).
// ---------------------------------------------------------------------------
__global__ __launch_bounds__(256) void bin_pass(const int* __restrict__ ei,
                                                int* __restrict__ g_count,
                                                int* __restrict__ bucket_mem)
{
    __shared__ int cnt[NB], base[NB], cnt2[NB];
    const int tid = threadIdx.x;
    for (int i = tid; i < NB; i += 256) { cnt[i] = 0; cnt2[i] = 0; }
    __syncthreads();

    const int e0 = blockIdx.x * P1_CHUNK;
    int srcv[16], dstv[16];
#pragma unroll
    for (int i = 0; i < 16; i++) {
        int eid = e0 + i * 256 + tid;   // coalesced
        int s = 0, d = -1;
        if (eid < ET) {
            if (eid < N_EDGES) { s = ei[eid]; d = ei[N_EDGES + eid]; }
            else               { s = d = eid - N_EDGES; }
        }
        srcv[i] = s; dstv[i] = d;
        if (d >= 0) atomicAdd(&cnt[d >> 8], 1);
    }
    __syncthreads();
    for (int i = tid; i < NB; i += 256)
        base[i] = (cnt[i] > 0) ? atomicAdd(&g_count[i], cnt[i]) : 0;
    __syncthreads();
#pragma unroll
    for (int i = 0; i < 16; i++) {
        int d = dstv[i];
        if (d >= 0) {
            int b = d >> 8;
            int r = atomicAdd(&cnt2[b], 1);
            int slot = base[b] + r;
            if (slot < BCAP)
                bucket_mem[(size_t)b * BCAP + slot] =
                    (srcv[i] & 0xFFFF) | ((d & 255) << 16);
        }
    }
}

__global__ __launch_bounds__(256) void csr_pass(const int* __restrict__ g_count,
                                                const int* __restrict__ bucket_mem,
                                                int* __restrict__ row_ptr,
                                                unsigned short* __restrict__ csr_src)
{
    __shared__ int sh_edges[BCAP];
    __shared__ int hist[256], offs[256], excl[256], cnt2[256];
    __shared__ int gsc[256];
    const int b = blockIdx.x, tid = threadIdx.x;

    gsc[tid] = (tid < NB) ? g_count[tid] : 0;
    __syncthreads();
    for (int d = 1; d < 256; d <<= 1) {
        int x = (tid >= d) ? gsc[tid - d] : 0;
        __syncthreads();
        gsc[tid] += x;
        __syncthreads();
    }
    const int base_csr = (b > 0) ? gsc[b - 1] : 0;

    int m = g_count[b]; if (m > BCAP) m = BCAP;
    hist[tid] = 0; cnt2[tid] = 0;
    __syncthreads();
    const int* bm = bucket_mem + (size_t)b * BCAP;
    for (int i = tid; i < m; i += 256) {
        int p = bm[i];
        sh_edges[i] = p;
        atomicAdd(&hist[(p >> 16) & 255], 1);
    }
    __syncthreads();
    offs[tid] = hist[tid]; __syncthreads();
    for (int d = 1; d < 256; d <<= 1) {
        int x = (tid >= d) ? offs[tid - d] : 0;
        __syncthreads();
        offs[tid] += x;
        __syncthreads();
    }
    excl[tid] = offs[tid] - hist[tid];
    const int node0 = b << 8;
    if (node0 + tid < N_NODES) row_ptr[node0 + tid] = base_csr + excl[tid];
    if (b == 0 && tid == 0) row_ptr[N_NODES] = ET;
    __syncthreads();
    for (int i = tid; i < m; i += 256) {
        int p = sh_edges[i];
        int dl = (p >> 16) & 255;
        int r = atomicAdd(&cnt2[dl], 1);
        csr_src[base_csr + excl[dl] + r] = (unsigned short)(p & 0xFFFF);
    }
}

// ---------------------------------------------------------------------------
// Head-PAIR fused scores + softmax + aggregate. XL fp16 (halved gather bytes,
// 6.4 MB/pair pool), XR fp32. grid = (ceil(N/4), 2). One wave per (node,pair).
// 8 lanes/edge, 8 ch/lane, 8 edges in flight. out standard [N][128] fp32.
// ---------------------------------------------------------------------------
__global__ __launch_bounds__(256) void fused_agg(
    const _Float16* __restrict__ XL, const float* __restrict__ XR,
    const int* __restrict__ row_ptr, const unsigned short* __restrict__ csr_src,
    const float* __restrict__ att, const float* __restrict__ bias,
    float* __restrict__ out)
{
    const int t = threadIdx.x;
    const int wave = t >> 6, l = t & 63;
    const int g = l >> 3, gl = l & 7;        // edge group 0..7, lane in group
    const int hp = blockIdx.y;               // head pair
    const int n = blockIdx.x * 4 + wave;
    if (n >= N_NODES) return;
    const int beg = row_ptr[n], end = row_ptr[n + 1];

    const _Float16* xlp = XL + (size_t)hp * N_NODES * 64;
    const int c0 = gl * 8;                   // channel within pair (0..56)
    const float* xrp = XR + ((size_t)hp * N_NODES + n) * 64 + c0;
    float4 xr0 = *(const float4*)(xrp);
    float4 xr1 = *(const float4*)(xrp + 4);
    float4 at0 = *(const float4*)(att + hp * 64 + c0);
    float4 at1 = *(const float4*)(att + hp * 64 + c0 + 4);

    float a0 = 0.f, a1 = 0.f, a2 = 0.f, a3 = 0.f;
    float a4 = 0.f, a5 = 0.f, a6 = 0.f, a7 = 0.f, den = 0.f;

    for (int base = beg; base < end; base += 64) {
        int cnt = end - base; if (cnt > 64) cnt = 64;
        int my_src = 0;
        if (base + l < end) my_src = csr_src[base + l];   // coalesced batch load
        int jmax = (cnt + 7) >> 3;
        for (int j = 0; j < jmax; j++) {
            int eidx = j * 8 + g;
            int s = __shfl(my_src, eidx);                 // row 0 if OOB (masked)
            half8 hv = *(const half8*)(xlp + (size_t)s * 64 + c0);
            float v0 = (float)hv[0], v1 = (float)hv[1];
            float v2 = (float)hv[2], v3 = (float)hv[3];
            float v4 = (float)hv[4], v5 = (float)hv[5];
            float v6 = (float)hv[6], v7 = (float)hv[7];
            float m0 = v0 + xr0.x, m1 = v1 + xr0.y;
            float m2 = v2 + xr0.z, m3 = v3 + xr0.w;
            float m4 = v4 + xr1.x, m5 = v5 + xr1.y;
            float m6 = v6 + xr1.z, m7 = v7 + xr1.w;
            m0 = m0 > 0.f ? m0 : SLOPE * m0;  m1 = m1 > 0.f ? m1 : SLOPE * m1;
            m2 = m2 > 0.f ? m2 : SLOPE * m2;  m3 = m3 > 0.f ? m3 : SLOPE * m3;
            m4 = m4 > 0.f ? m4 : SLOPE * m4;  m5 = m5 > 0.f ? m5 : SLOPE * m5;
            m6 = m6 > 0.f ? m6 : SLOPE * m6;  m7 = m7 > 0.f ? m7 : SLOPE * m7;
            float p = m0 * at0.x + m1 * at0.y + m2 * at0.z + m3 * at0.w
                    + m4 * at1.x + m5 * at1.y + m6 * at1.z + m7 * at1.w;
            // per-head reduce: lanes {0-3} = head 2hp, {4-7} = head 2hp+1
            p += __shfl_xor(p, 1);
            p += __shfl_xor(p, 2);
            float e = (eidx < cnt) ? __expf(p) : 0.f;
            a0 += e * v0; a1 += e * v1; a2 += e * v2; a3 += e * v3;
            a4 += e * v4; a5 += e * v5; a6 += e * v6; a7 += e * v7;
            den += e;
        }
    }

    // combine the 8 edge-group accumulators (same channels, different edges)
#define CMB(x) x += __shfl_xor(x, 8); x += __shfl_xor(x, 16); x += __shfl_xor(x, 32);
    CMB(a0) CMB(a1) CMB(a2) CMB(a3) CMB(a4) CMB(a5) CMB(a6) CMB(a7) CMB(den)
#undef CMB

    if (g == 0) {
        float inv = 1.f / (den + 1e-16f);
        const float* bp = bias + hp * 64 + c0;
        float4 b0 = *(const float4*)(bp);
        float4 b1 = *(const float4*)(bp + 4);
        float4 o0, o1;
        o0.x = fmaxf(a0 * inv + b0.x, 0.f);
        o0.y = fmaxf(a1 * inv + b0.y, 0.f);
        o0.z = fmaxf(a2 * inv + b0.z, 0.f);
        o0.w = fmaxf(a3 * inv + b0.w, 0.f);
        o1.x = fmaxf(a4 * inv + b1.x, 0.f);
        o1.y = fmaxf(a5 * inv + b1.y, 0.f);
        o1.z = fmaxf(a6 * inv + b1.z, 0.f);
        o1.w = fmaxf(a7 * inv + b1.w, 0.f);
        float* op = out + (size_t)n * DF + hp * 64 + c0;
        *(float4*)(op)     = o0;
        *(float4*)(op + 4) = o1;
    }
}

// ---------------------------------------------------------------------------
extern "C" void kernel_launch(void* const* d_in, const int* in_sizes, int n_in,
                              void* d_out, int out_size, void* d_ws, size_t ws_size,
                              hipStream_t stream)
{
    (void)in_sizes; (void)n_in; (void)out_size; (void)ws_size;

    const float* x    = (const float*)d_in[0];
    const int*   ei   = (const int*)d_in[1];
    const float* W1l  = (const float*)d_in[2];
    const float* W1r  = (const float*)d_in[3];
    const float* att1 = (const float*)d_in[4];
    const float* b1   = (const float*)d_in[5];
    const float* W2l  = (const float*)d_in[6];
    const float* W2r  = (const float*)d_in[7];
    const float* att2 = (const float*)d_in[8];
    const float* b2   = (const float*)d_in[9];
    float* out = (float*)d_out;

    char* ws = (char*)d_ws;
    size_t off = 0;
    const size_t NF = (size_t)N_NODES * DF * sizeof(float);        // 25.6 MB
    _Float16* A = (_Float16*)(ws + off); off += NF / 2;            // xl fp16 pair-major
    float* B  = (float*)(ws + off); off += NF;                     // xr fp32 pair-major
    float* C  = (float*)(ws + off); off += NF;                     // layer-1 out (std)
    int* bucket_mem  = (int*)(ws + off); off += (size_t)NB * BCAP * sizeof(int);
    int* g_count     = (int*)(ws + off); off += 256 * sizeof(int);
    int* row_ptr     = (int*)(ws + off); off += (size_t)(N_NODES + 1) * sizeof(int);
    unsigned short* csr_src = (unsigned short*)(ws + off);
    off += ((size_t)ET * sizeof(unsigned short) + 255) & ~(size_t)255;
    unsigned short* Wh = (unsigned short*)(ws + off); off += 4 * 16384 * sizeof(unsigned short);
    unsigned short* Wl = (unsigned short*)(ws + off); off += 4 * 16384 * sizeof(unsigned short);

    // ---- one-time prep (wconv also zeroes g_count) ----
    wconv4<<<dim3(64, 4), 256, 0, stream>>>(W1l, W1r, W2l, W2r, Wh, Wl, g_count);
    bin_pass<<<(ET + P1_CHUNK - 1) / P1_CHUNK, 256, 0, stream>>>(ei, g_count, bucket_mem);
    csr_pass<<<NB, 256, 0, stream>>>(g_count, bucket_mem, row_ptr, csr_src);

    dim3 gg((N_NODES + 63) / 64);
    dim3 ga((N_NODES + 3) / 4, 2);

    // ---- layer 1 ----
    gemm_mfma<<<gg, 256, 0, stream>>>(x, Wh, Wl, Wh + 16384, Wl + 16384, A, B, N_NODES);
    fused_agg<<<ga, 256, 0, stream>>>(A, B, row_ptr, csr_src, att1, b1, C);

    // ---- layer 2 ----
    gemm_mfma<<<gg, 256, 0, stream>>>(C, Wh + 2 * 16384, Wl + 2 * 16384,
                                      Wh + 3 * 16384, Wl + 3 * 16384, A, B, N_NODES);
    fused_agg<<<ga, 256, 0, stream>>>(A, B, row_ptr, csr_src, att2, b2, out);
}